// Round 1
// baseline (321.617 us; speedup 1.0000x reference)
//
#include <hip/hip_runtime.h>

#define SIG_LEN 2048
#define LM1F 2047.0f
#define N_ITER 15
#define TPB 128          // tasks (= threads) per block
#define WIN 96           // window floats per task, 16B-aligned base
#define NF4 24           // WIN/4 float4 chunks per task
#define WPAD 97          // padded LDS stride; odd -> bank-decorrelated (iter-0 center
                         // offset is 47 for ALL lanes; stride 96 would be 64-way conflict)

// Window coverage proof (unchanged from prior session, re-derived for aligned base):
//   |dpos| <= sum ss_i*ms_i = 0.01008, eps reach 0.01 -> p within +-0.0201 of p0
//   -> index reach +-41.2, +1 for floor/ceil -> need [fl-43, fl+44].
//   base = clip(fl-47, 0, 1952) & ~3 in {fl-50..fl-47} (interior) -> window
//   [base, base+95] spans at worst [fl-50, fl+45] >= needed. Edge clips 0 and
//   1952 are 16B-aligned and cover [0,95] / [1952,2047]; all sample indices
//   stay in [0,2047] by construction.

__global__ __launch_bounds__(TPB) void refine_kernel(
    const float* __restrict__ init,
    const float* __restrict__ signals,
    float* __restrict__ out)
{
    __shared__ float win[TPB * WPAD];   // 49664 B -> 3 blocks/CU, 768 blocks = 3/CU exact
    __shared__ int   wbase[TPB];

    const int tid   = threadIdx.x;
    const int task0 = blockIdx.x * TPB;
    const int task  = task0 + tid;      // n = 98304 = 768 * 128 exactly, no guard

    // ---- phase 1: per-task window base (16B-aligned) ----
    const float p0 = init[task];
    float pp = fminf(fmaxf(__fmul_rn(p0, LM1F), 0.0f), LM1F);
    int base = (int)floorf(pp) - 47;
    base = min(max(base, 0), SIG_LEN - WIN);
    base &= ~3;                          // align down to float4; coverage proven above
    wbase[tid] = base;
    __syncthreads();

    // ---- phase 2: cooperative coalesced float4 staging ----
    // 3072 float4 per block, 24 per thread. Consecutive lanes -> consecutive 16B
    // chunks of a task's contiguous 384B segment (group of 24 lanes per task).
    #pragma unroll
    for (int k = tid; k < TPB * NF4; k += TPB) {
        int t = k / NF4;                 // const-div -> magic mul
        int j = k - t * NF4;
        int row = (task0 + t) / 3;
        const float4 v = *reinterpret_cast<const float4*>(
            &signals[(size_t)row * SIG_LEN + (wbase[t] + 4 * j)]);
        int d = t * WPAD + 4 * j;
        win[d]     = v.x;
        win[d + 1] = v.y;
        win[d + 2] = v.z;
        win[d + 3] = v.w;
    }
    __syncthreads();

    // ---- phase 3: all 15 iterations out of LDS ----
    // Pointer pre-offset so global il indexes directly.
    const float* __restrict__ w = &win[tid * WPAD] - base;

    float pos = p0;
    float ss = 0.01f;

    const float ms_tab[N_ITER] = {
        0.2f, 0.18f, 0.162f, 0.1458f, 0.13122f,
        0.118098f, 0.1062882f, 0.09565938f, 0.086093442f, 0.0774840978f,
        0.06973568802f, 0.062762119218f, 0.0564859072962f, 0.05083731656658f,
        0.045753584909922f
    };

    const float eps_arr[3] = {0.001f, 0.003f, 0.01f};
    const float ome_arr[3] = {0.999f, 0.997f, 0.99f};
    const float wgt_arr[3] = {0.5f, 0.3f, 0.2f};
    const float te_arr[3]  = {0.002f, 0.006f, 0.02f};
    const float es_arr[3]  = {1e-06f, 9e-06f, 1e-04f};

    #pragma unroll
    for (int it = 0; it < N_ITER; ++it) {
        // -- address prep for all 9 samples (exact _sample front-end per sample) --
        int   adl[9], adr[9];
        float wr9[9];
        #pragma unroll
        for (int s = 0; s < 3; ++s) {
            float pc = fminf(fmaxf(pos, eps_arr[s]), ome_arr[s]);
            float qs0 = pc;
            float qs1 = __fsub_rn(pc, eps_arr[s]);
            float qs2 = __fadd_rn(pc, eps_arr[s]);
            float qs[3] = {qs0, qs1, qs2};
            #pragma unroll
            for (int u = 0; u < 3; ++u) {
                const int i9 = s * 3 + u;
                float p  = fminf(fmaxf(__fmul_rn(qs[u], LM1F), 0.0f), LM1F);
                float fl = floorf(p);
                int   il = (int)fl;
                adl[i9] = il;
                adr[i9] = il + ((p > fl) ? 1 : 0);   // ceil via floor + (p>fl)
                wr9[i9] = __fsub_rn(p, fl);
            }
        }
        // -- one 18-deep LDS load batch --
        float vla[9], vra[9];
        #pragma unroll
        for (int i9 = 0; i9 < 9; ++i9) {
            vla[i9] = w[adl[i9]];
            vra[i9] = w[adr[i9]];
        }
        // -- lerps (exact reference op order) --
        float sv[9];
        #pragma unroll
        for (int i9 = 0; i9 < 9; ++i9) {
            sv[i9] = __fadd_rn(__fmul_rn(__fsub_rn(1.0f, wr9[i9]), vla[i9]),
                               __fmul_rn(wr9[i9], vra[i9]));
        }
        // -- accumulate g, c in original association order: ((t0 + t1) + t2) --
        float g = 0.0f, c = 0.0f;
        #pragma unroll
        for (int s = 0; s < 3; ++s) {
            float v  = sv[s * 3 + 0];
            float vl = sv[s * 3 + 1];
            float vr = sv[s * 3 + 2];
            g = __fadd_rn(g, __fmul_rn(wgt_arr[s], __fsub_rn(vr, vl)) / te_arr[s]);
            float t2 = __fsub_rn(__fadd_rn(vr, vl), __fmul_rn(2.0f, v));
            c = __fadd_rn(c, __fmul_rn(wgt_arr[s], t2) / es_arr[s]);
        }

        c = fminf(fmaxf(c, -1000.0f), 1000.0f);
        float step = (-g) / __fadd_rn(fabsf(c), 1e-06f);
        float ms = ms_tab[it];
        step = fminf(fmaxf(step, -ms), ms);
        pos = fminf(fmaxf(__fadd_rn(pos, __fmul_rn(ss, step)), 0.0f), 1.0f);
        ss = __fmul_rn(ss, 0.9f);
    }

    out[task] = pos;
}

extern "C" void kernel_launch(void* const* d_in, const int* in_sizes, int n_in,
                              void* d_out, int out_size, void* d_ws, size_t ws_size,
                              hipStream_t stream) {
    const float* init    = (const float*)d_in[0];   // (32768, 3) f32
    const float* signals = (const float*)d_in[1];   // (32768, 2048) f32
    float* out = (float*)d_out;                     // (32768, 3) f32

    int n = out_size;                               // 98304
    int grid = n / TPB;                             // 768
    refine_kernel<<<grid, TPB, 0, stream>>>(init, signals, out);
}